// Round 8
// baseline (270.248 us; speedup 1.0000x reference)
//
#include <hip/hip_runtime.h>
#include <math.h>

#define D 64
#define SCAN_ELEMS 1024   // elements per scan block (256 thr x 4)
#define FILL_K 8          // edges per thread in bucketed edge kernels

// NOTE: node ids fit in ushort (N=50000 < 65536) — CSR vals stored as u16.

// ---------------------------------------------------------------------------
// zero int array
// ---------------------------------------------------------------------------
__global__ void zero_int(int* __restrict__ p, int n) {
    int i = blockIdx.x * blockDim.x + threadIdx.x;
    int stride = gridDim.x * blockDim.x;
    for (; i < n; i += stride) p[i] = 0;
}

// ---------------------------------------------------------------------------
// histogram, XCD-bucketed: WG w handles only nodes in bucket (w&7).
// Edge reads are NON-TEMPORAL: they stream 6.4MB/XCD through L2 and were
// evicting the dirty counter lines (R7 lesson); nt keeps L2 for the atomics.
// ---------------------------------------------------------------------------
__global__ __launch_bounds__(256) void hist(
    const int* __restrict__ src, const int* __restrict__ dst,
    int* __restrict__ deg, int nE, int nN, int bshift) {
    int w = blockIdx.x;
    int bucket = w & 7;
    int chunk = w >> 3;
    int base = chunk * (256 * FILL_K) + threadIdx.x;
#pragma unroll
    for (int k = 0; k < FILL_K; ++k) {
        int e = base + k * 256;
        if (e < nE) {
            int s = __builtin_nontemporal_load(src + e);
            int t = __builtin_nontemporal_load(dst + e);
            if ((t >> bshift) == bucket) atomicAdd(&deg[t], 1);
            if ((s >> bshift) == bucket) atomicAdd(&deg[nN + s], 1);
        }
    }
}

// ---------------------------------------------------------------------------
// scan pass 1: per-block sums of deg chunks
// ---------------------------------------------------------------------------
__global__ __launch_bounds__(256) void scan_part(
    const int* __restrict__ deg, int* __restrict__ bsum, int n) {
    __shared__ int sdata[256];
    int b = blockIdx.x, t = threadIdx.x;
    int base = b * SCAN_ELEMS + t * 4;
    int s = 0;
#pragma unroll
    for (int k = 0; k < 4; ++k) { int i = base + k; if (i < n) s += deg[i]; }
    sdata[t] = s;
    __syncthreads();
    for (int o = 128; o > 0; o >>= 1) {
        if (t < o) sdata[t] += sdata[t + o];
        __syncthreads();
    }
    if (t == 0) bsum[b] = sdata[0];
}

// ---------------------------------------------------------------------------
// scan pass 2: exclusive scan of block sums (nb <= 256), in place.
// ---------------------------------------------------------------------------
__global__ __launch_bounds__(256) void scan_tops(
    int* __restrict__ bsum, int nb, int* __restrict__ off, int total, int n) {
    __shared__ int sd[256];
    int t = threadIdx.x;
    int v = (t < nb) ? bsum[t] : 0;
    sd[t] = v;
    __syncthreads();
    for (int o = 1; o < 256; o <<= 1) {
        int u = (t >= o) ? sd[t - o] : 0;
        __syncthreads();
        sd[t] += u;
        __syncthreads();
    }
    if (t < nb) bsum[t] = sd[t] - v;   // exclusive
    if (t == 0) off[n] = total;
}

// ---------------------------------------------------------------------------
// scan pass 3: per-chunk exclusive scan + block offset -> off[] and cur[]
// ---------------------------------------------------------------------------
__global__ __launch_bounds__(256) void scan_final(
    const int* __restrict__ deg, const int* __restrict__ bsum,
    int* __restrict__ off, int* __restrict__ cur, int n) {
    __shared__ int sth[256];
    int b = blockIdx.x, t = threadIdx.x;
    int base = b * SCAN_ELEMS + t * 4;
    int v[4]; int s = 0;
#pragma unroll
    for (int k = 0; k < 4; ++k) { int i = base + k; v[k] = (i < n) ? deg[i] : 0; s += v[k]; }
    sth[t] = s;
    __syncthreads();
    for (int o = 1; o < 256; o <<= 1) {
        int u = (t >= o) ? sth[t - o] : 0;
        __syncthreads();
        sth[t] += u;
        __syncthreads();
    }
    int run = sth[t] - s + bsum[b];    // exclusive prefix for this thread
#pragma unroll
    for (int k = 0; k < 4; ++k) {
        int i = base + k;
        if (i < n) { off[i] = run; cur[i] = run; run += v[k]; }
    }
}

// ---------------------------------------------------------------------------
// fill CSR (u16 entries), XCD-bucketed + NON-TEMPORAL edge reads.
// R7 diagnosis: WRITE_SIZE 63MB for a 3.2MB payload = dirty vals lines
// repeatedly evicted by the clean 6.4MB/XCD edge-read stream. nt loads keep
// the read stream out of L2 so partially-filled vals lines stay resident
// until full. vals[0..E): src grouped by dst. vals[E..2E): dst grouped by
// src (off[] second-section values already index [E,2E) — don't re-offset!)
// ---------------------------------------------------------------------------
__global__ __launch_bounds__(256) void fill_csr(
    const int* __restrict__ src, const int* __restrict__ dst,
    int* __restrict__ cur, unsigned short* __restrict__ vals,
    int nE, int nN, int bshift) {
    int w = blockIdx.x;
    int bucket = w & 7;
    int chunk = w >> 3;
    int base = chunk * (256 * FILL_K) + threadIdx.x;
#pragma unroll
    for (int k = 0; k < FILL_K; ++k) {
        int e = base + k * 256;
        if (e < nE) {
            int s = __builtin_nontemporal_load(src + e);
            int t = __builtin_nontemporal_load(dst + e);
            if ((t >> bshift) == bucket) {
                int p = atomicAdd(&cur[t], 1);
                vals[p] = (unsigned short)s;
            }
            if ((s >> bshift) == bucket) {
                int p2 = atomicAdd(&cur[nN + s], 1);
                vals[p2] = (unsigned short)t;
            }
        }
    }
}

// ---------------------------------------------------------------------------
// Kernel A: 512-thread blocks = 8 node-waves sharing one W staging (LDS
// 36864B -> 4 blocks/CU -> 32 waves/CU). Per wave: 4 lane-groups of 16 each
// gather a different incoming X row as float4 (1KB/wave/instr), butterfly-
// reduce, then fused dual 64x64 GEMM+bias+ReLU.
// sW stride 64 conflict-free: k wave-uniform, j=lane -> 2-way aliasing free.
// ---------------------------------------------------------------------------
#define ANODES 8
__global__ __launch_bounds__(512) void agg_gemm(
    const float* __restrict__ X,
    const int* __restrict__ off,              // [2N+1]
    const unsigned short* __restrict__ vals,  // [2E]
    const float* __restrict__ Wn, const float* __restrict__ Ws,
    const float* __restrict__ bias,
    float* __restrict__ h, int nNodes) {
    __shared__ float sWn[D][D];
    __shared__ float sWs[D][D];
    __shared__ float rowA[ANODES][D];
    __shared__ float rowX[ANODES][D];

    int t = threadIdx.x;
    for (int i = t; i < D * D; i += 512) {
        sWn[i >> 6][i & 63] = Wn[i];
        sWs[i >> 6][i & 63] = Ws[i];
    }

    int li = t >> 6;       // wave id = local node 0..7
    int lane = t & 63;
    int g = lane >> 4;     // edge group 0..3
    int q = lane & 15;     // float4 index: dims 4q..4q+3
    int node = blockIdx.x * ANODES + li;

    float ax = 0.f, ay = 0.f, az = 0.f, aw = 0.f;
    int beg = 0, end = 0;
    if (node < nNodes) { beg = off[node]; end = off[node + 1]; }

    int base = beg;
    for (; base + 8 <= end; base += 8) {
        int s0 = vals[base + g];
        int s1 = vals[base + 4 + g];
        float4 v0 = ((const float4*)(X + (size_t)s0 * D))[q];
        float4 v1 = ((const float4*)(X + (size_t)s1 * D))[q];
        ax += v0.x + v1.x; ay += v0.y + v1.y;
        az += v0.z + v1.z; aw += v0.w + v1.w;
    }
    for (; base < end; base += 4) {
        int e = base + g;
        if (e < end) {
            int s = vals[e];
            float4 v = ((const float4*)(X + (size_t)s * D))[q];
            ax += v.x; ay += v.y; az += v.z; aw += v.w;
        }
    }
    // reduce across the 4 edge-groups (lanes differing in bits 4,5)
#pragma unroll
    for (int o = 16; o <= 32; o <<= 1) {
        ax += __shfl_xor(ax, o); ay += __shfl_xor(ay, o);
        az += __shfl_xor(az, o); aw += __shfl_xor(aw, o);
    }

    if (node < nNodes && g == 0) {
        float inv = 1.0f / fmaxf((float)(end - beg), 1.0f);
        float4 r; r.x = ax * inv; r.y = ay * inv; r.z = az * inv; r.w = aw * inv;
        ((float4*)&rowA[li][0])[q] = r;
        ((float4*)&rowX[li][0])[q] = ((const float4*)(X + (size_t)node * D))[q];
    }
    __syncthreads();
    if (node >= nNodes) return;

    int j = lane;
    float accj = bias[j];
#pragma unroll
    for (int k = 0; k < D; ++k) {
        accj += rowA[li][k] * sWn[k][j] + rowX[li][k] * sWs[k][j];
    }
    h[(size_t)node * D + j] = fmaxf(accj, 0.0f);
}

// ---------------------------------------------------------------------------
// Kernel B: per-node wave; same 4x16 group structure over outgoing edges;
// squared diffs vs in-register h[node]; tanh(mean) -> out.
// off[nNodes+node] already indexes the second vals section [E,2E).
// ---------------------------------------------------------------------------
__global__ __launch_bounds__(256) void m_gather(
    const float* __restrict__ h,
    const int* __restrict__ off,              // [2N+1], src section at [N..2N]
    const unsigned short* __restrict__ vals,  // [2E]
    float* __restrict__ out, int nNodes) {
    int t = threadIdx.x;
    int li = t >> 6;
    int lane = t & 63;
    int g = lane >> 4;
    int q = lane & 15;
    int node = blockIdx.x * 4 + li;
    if (node >= nNodes) return;

    float4 hn = ((const float4*)(h + (size_t)node * D))[q];
    int beg = off[nNodes + node];
    int end = off[nNodes + node + 1];

    float ax = 0.f, ay = 0.f, az = 0.f, aw = 0.f;
    int base = beg;
    for (; base + 8 <= end; base += 8) {
        int t0 = vals[base + g];
        int t1 = vals[base + 4 + g];
        float4 u0 = ((const float4*)(h + (size_t)t0 * D))[q];
        float4 u1 = ((const float4*)(h + (size_t)t1 * D))[q];
        float dx0 = hn.x - u0.x, dy0 = hn.y - u0.y, dz0 = hn.z - u0.z, dw0 = hn.w - u0.w;
        float dx1 = hn.x - u1.x, dy1 = hn.y - u1.y, dz1 = hn.z - u1.z, dw1 = hn.w - u1.w;
        ax += dx0 * dx0 + dx1 * dx1; ay += dy0 * dy0 + dy1 * dy1;
        az += dz0 * dz0 + dz1 * dz1; aw += dw0 * dw0 + dw1 * dw1;
    }
    for (; base < end; base += 4) {
        int e = base + g;
        if (e < end) {
            int tt = vals[e];
            float4 u = ((const float4*)(h + (size_t)tt * D))[q];
            float dx = hn.x - u.x, dy = hn.y - u.y, dz = hn.z - u.z, dw = hn.w - u.w;
            ax += dx * dx; ay += dy * dy; az += dz * dz; aw += dw * dw;
        }
    }
#pragma unroll
    for (int o = 16; o <= 32; o <<= 1) {
        ax += __shfl_xor(ax, o); ay += __shfl_xor(ay, o);
        az += __shfl_xor(az, o); aw += __shfl_xor(aw, o);
    }

    if (g == 0) {
        float inv = 1.0f / fmaxf((float)(end - beg), 1.0f);
        float4 r;
        r.x = tanhf(ax * inv); r.y = tanhf(ay * inv);
        r.z = tanhf(az * inv); r.w = tanhf(aw * inv);
        ((float4*)(out + (size_t)node * D))[q] = r;
    }
}

extern "C" void kernel_launch(void* const* d_in, const int* in_sizes, int n_in,
                              void* d_out, int out_size, void* d_ws, size_t ws_size,
                              hipStream_t stream) {
    const float* X  = (const float*)d_in[0];
    const int*   ei = (const int*)d_in[1];   // int32 (JAX canonicalized)
    const float* Wn = (const float*)d_in[2];
    const float* Ws = (const float*)d_in[3];
    const float* b  = (const float*)d_in[4];
    float* out = (float*)d_out;

    int nNodes = in_sizes[0] / D;
    int nEdges = in_sizes[1] / 2;
    const int* src = ei;
    const int* dst = ei + nEdges;

    int n2 = 2 * nNodes;
    int nb = (n2 + SCAN_ELEMS - 1) / SCAN_ELEMS;

    // node -> bucket via shift: smallest bshift with (nNodes-1)>>bshift <= 7
    int bshift = 0;
    while (((nNodes - 1) >> bshift) > 7) bshift++;

    // workspace (16B-aligned sections):
    // deg[2N] | off[2N+1] | cur[2N] | bsum[256] | vals_u16[2E] | h[N*D]
    size_t o = 0;
    auto align4 = [](size_t x) { return (x + 3) & ~(size_t)3; };  // 4B elems -> 16B
    int* deg  = (int*)d_ws;                 o = align4((size_t)n2);
    int* off  = (int*)d_ws + o;             o = align4(o + (size_t)n2 + 1);
    int* cur  = (int*)d_ws + o;             o = align4(o + (size_t)n2);
    int* bsum = (int*)d_ws + o;             o = align4(o + 256);
    unsigned short* vals = (unsigned short*)((int*)d_ws + o);
    o = align4(o + (size_t)nEdges);         // 2E ushorts == E ints
    float* h  = (float*)((int*)d_ws + o);

    zero_int<<<256, 256, 0, stream>>>(deg, n2);

    int chunks = (nEdges + 256 * FILL_K - 1) / (256 * FILL_K);
    int eGrid = chunks * 8;
    hist<<<eGrid, 256, 0, stream>>>(src, dst, deg, nEdges, nNodes, bshift);

    scan_part<<<nb, 256, 0, stream>>>(deg, bsum, n2);
    scan_tops<<<1, 256, 0, stream>>>(bsum, nb, off, 2 * nEdges, n2);
    scan_final<<<nb, 256, 0, stream>>>(deg, bsum, off, cur, n2);

    fill_csr<<<eGrid, 256, 0, stream>>>(src, dst, cur, vals, nEdges, nNodes, bshift);

    int aBlocks = (nNodes + ANODES - 1) / ANODES;
    agg_gemm<<<aBlocks, 512, 0, stream>>>(X, off, vals, Wn, Ws, b, h, nNodes);
    int mBlocks = (nNodes + 3) / 4;
    m_gather<<<mBlocks, 256, 0, stream>>>(h, off, vals, out, nNodes);
}

// Round 9
// 144.512 us; speedup vs baseline: 1.8701x; 1.8701x over previous
//
#include <hip/hip_runtime.h>
#include <math.h>

#define D 64
#define SCAN_ELEMS 1024    // elements per scan block (256 thr x 4)
#define STEP 256           // nodes per partition bucket (key space 2N)
#define SHIFT 8            // log2(STEP)
#define PART_CHUNK 2048    // edges per partition WG

// Node ids fit u16 (N=50000 < 65536). Partition items are packed u32:
// (key_local_to_bucket << 16) | other_node.

// ---------------------------------------------------------------------------
// part_hist: per-WG histogram of items into K coarse buckets (LDS counters).
// Each edge contributes 2 items: key=dst (in-CSR) and key=N+src (out-CSR).
// cnt layout is bucket-major: cnt[b*WGs + wg].
// ---------------------------------------------------------------------------
__global__ __launch_bounds__(256) void part_hist(
    const int* __restrict__ src, const int* __restrict__ dst,
    int* __restrict__ cnt, int nE, int nN, int K, int WGs) {
    __shared__ int lh[1024];
    int wg = blockIdx.x;
    for (int i = threadIdx.x; i < K; i += 256) lh[i] = 0;
    __syncthreads();
    int base = wg * PART_CHUNK;
    int lim = min(base + PART_CHUNK, nE);
    for (int e = base + threadIdx.x; e < lim; e += 256) {
        int s = src[e], t = dst[e];
        atomicAdd(&lh[t >> SHIFT], 1);
        atomicAdd(&lh[(nN + s) >> SHIFT], 1);
    }
    __syncthreads();
    for (int b = threadIdx.x; b < K; b += 256) cnt[b * WGs + wg] = lh[b];
}

// ---------------------------------------------------------------------------
// scan pass 1: per-block sums of cnt chunks
// ---------------------------------------------------------------------------
__global__ __launch_bounds__(256) void scan_part(
    const int* __restrict__ in, int* __restrict__ bsum, int n) {
    __shared__ int sdata[256];
    int b = blockIdx.x, t = threadIdx.x;
    int base = b * SCAN_ELEMS + t * 4;
    int s = 0;
#pragma unroll
    for (int k = 0; k < 4; ++k) { int i = base + k; if (i < n) s += in[i]; }
    sdata[t] = s;
    __syncthreads();
    for (int o = 128; o > 0; o >>= 1) {
        if (t < o) sdata[t] += sdata[t + o];
        __syncthreads();
    }
    if (t == 0) bsum[b] = sdata[0];
}

// ---------------------------------------------------------------------------
// scan pass 2: exclusive scan of block sums in place (nb <= 256)
// ---------------------------------------------------------------------------
__global__ __launch_bounds__(256) void scan_tops(int* __restrict__ bsum, int nb) {
    __shared__ int sd[256];
    int t = threadIdx.x;
    int v = (t < nb) ? bsum[t] : 0;
    sd[t] = v;
    __syncthreads();
    for (int o = 1; o < 256; o <<= 1) {
        int u = (t >= o) ? sd[t - o] : 0;
        __syncthreads();
        sd[t] += u;
        __syncthreads();
    }
    if (t < nb) bsum[t] = sd[t] - v;   // exclusive
}

// ---------------------------------------------------------------------------
// scan pass 3: per-chunk exclusive scan + block offset -> out
// ---------------------------------------------------------------------------
__global__ __launch_bounds__(256) void scan_final(
    const int* __restrict__ in, const int* __restrict__ bsum,
    int* __restrict__ out, int n) {
    __shared__ int sth[256];
    int b = blockIdx.x, t = threadIdx.x;
    int base = b * SCAN_ELEMS + t * 4;
    int v[4]; int s = 0;
#pragma unroll
    for (int k = 0; k < 4; ++k) { int i = base + k; v[k] = (i < n) ? in[i] : 0; s += v[k]; }
    sth[t] = s;
    __syncthreads();
    for (int o = 1; o < 256; o <<= 1) {
        int u = (t >= o) ? sth[t - o] : 0;
        __syncthreads();
        sth[t] += u;
        __syncthreads();
    }
    int run = sth[t] - s + bsum[b];
#pragma unroll
    for (int k = 0; k < 4; ++k) {
        int i = base + k;
        if (i < n) { out[i] = run; run += v[k]; }
    }
}

// ---------------------------------------------------------------------------
// part_write: each WG writes its items into ITS OWN contiguous slice of each
// bucket region (slice base from scanned cnt). Every 64B line of part[] has
// <=2 writers, temporally adjacent -> writeback ~= payload (the R8 lesson:
// the scatter killer was many-writers-per-line spread over the whole kernel).
// ---------------------------------------------------------------------------
__global__ __launch_bounds__(256) void part_write(
    const int* __restrict__ src, const int* __restrict__ dst,
    const int* __restrict__ scanned, unsigned int* __restrict__ part,
    int nE, int nN, int K, int WGs) {
    __shared__ int cur[1024];
    int wg = blockIdx.x;
    for (int b = threadIdx.x; b < K; b += 256) cur[b] = scanned[b * WGs + wg];
    __syncthreads();
    int base = wg * PART_CHUNK;
    int lim = min(base + PART_CHUNK, nE);
    for (int e = base + threadIdx.x; e < lim; e += 256) {
        int s = src[e], t = dst[e];
        int k1 = t;
        int p1 = atomicAdd(&cur[k1 >> SHIFT], 1);
        part[p1] = ((unsigned)(k1 & (STEP - 1)) << 16) | (unsigned)s;
        int k2 = nN + s;
        int p2 = atomicAdd(&cur[k2 >> SHIFT], 1);
        part[p2] = ((unsigned)(k2 & (STEP - 1)) << 16) | (unsigned)t;
    }
}

// ---------------------------------------------------------------------------
// csr_build: one WG per bucket. Count per-node degrees in LDS, prefix-scan,
// write off[] exactly (no global hist needed), then scatter u16 vals into
// the WG-private ~8KB region — single owner + compact in time -> L2-merged.
// ---------------------------------------------------------------------------
__global__ __launch_bounds__(256) void csr_build(
    const unsigned int* __restrict__ part, const int* __restrict__ scanned,
    unsigned short* __restrict__ vals, int* __restrict__ off,
    int n2, int K, int WGs, int totalItems) {
    __shared__ int deg[STEP];
    __shared__ int pfx[STEP];
    int b = blockIdx.x, t = threadIdx.x;
    int base = scanned[b * WGs];
    int endi = (b + 1 < K) ? scanned[(b + 1) * WGs] : totalItems;

    deg[t] = 0;
    __syncthreads();
    for (int i = base + t; i < endi; i += 256)
        atomicAdd(&deg[part[i] >> 16], 1);
    __syncthreads();

    // exclusive prefix over STEP==blockDim elems
    pfx[t] = deg[t];
    __syncthreads();
    for (int o = 1; o < STEP; o <<= 1) {
        int u = (t >= o) ? pfx[t - o] : 0;
        __syncthreads();
        pfx[t] += u;
        __syncthreads();
    }
    int ex = pfx[t] - deg[t];
    int g = b * STEP + t;
    if (g < n2) off[g] = base + ex;
    if (b == K - 1 && t == 0) off[n2] = totalItems;
    deg[t] = ex;           // reuse as bucket-local cursor
    __syncthreads();

    for (int i = base + t; i < endi; i += 256) {
        unsigned u = part[i];
        int l = (int)(u >> 16);
        int p = atomicAdd(&deg[l], 1);
        vals[base + p] = (unsigned short)(u & 0xffffu);
    }
}

// ---------------------------------------------------------------------------
// Kernel A: 512-thread blocks = 8 node-waves sharing one W staging (LDS
// 36864B -> 4 blocks/CU -> 32 waves/CU). Per wave: 4 lane-groups of 16 each
// gather a different incoming X row as float4 (1KB/wave/instr), butterfly-
// reduce, then fused dual 64x64 GEMM+bias+ReLU.
// ---------------------------------------------------------------------------
#define ANODES 8
__global__ __launch_bounds__(512) void agg_gemm(
    const float* __restrict__ X,
    const int* __restrict__ off,              // [2N+1]
    const unsigned short* __restrict__ vals,  // [2E]
    const float* __restrict__ Wn, const float* __restrict__ Ws,
    const float* __restrict__ bias,
    float* __restrict__ h, int nNodes) {
    __shared__ float sWn[D][D];
    __shared__ float sWs[D][D];
    __shared__ float rowA[ANODES][D];
    __shared__ float rowX[ANODES][D];

    int t = threadIdx.x;
    for (int i = t; i < D * D; i += 512) {
        sWn[i >> 6][i & 63] = Wn[i];
        sWs[i >> 6][i & 63] = Ws[i];
    }

    int li = t >> 6;       // wave id = local node 0..7
    int lane = t & 63;
    int g = lane >> 4;     // edge group 0..3
    int q = lane & 15;     // float4 index: dims 4q..4q+3
    int node = blockIdx.x * ANODES + li;

    float ax = 0.f, ay = 0.f, az = 0.f, aw = 0.f;
    int beg = 0, end = 0;
    if (node < nNodes) { beg = off[node]; end = off[node + 1]; }

    int base = beg;
    for (; base + 8 <= end; base += 8) {
        int s0 = vals[base + g];
        int s1 = vals[base + 4 + g];
        float4 v0 = ((const float4*)(X + (size_t)s0 * D))[q];
        float4 v1 = ((const float4*)(X + (size_t)s1 * D))[q];
        ax += v0.x + v1.x; ay += v0.y + v1.y;
        az += v0.z + v1.z; aw += v0.w + v1.w;
    }
    for (; base < end; base += 4) {
        int e = base + g;
        if (e < end) {
            int s = vals[e];
            float4 v = ((const float4*)(X + (size_t)s * D))[q];
            ax += v.x; ay += v.y; az += v.z; aw += v.w;
        }
    }
#pragma unroll
    for (int o = 16; o <= 32; o <<= 1) {
        ax += __shfl_xor(ax, o); ay += __shfl_xor(ay, o);
        az += __shfl_xor(az, o); aw += __shfl_xor(aw, o);
    }

    if (node < nNodes && g == 0) {
        float inv = 1.0f / fmaxf((float)(end - beg), 1.0f);
        float4 r; r.x = ax * inv; r.y = ay * inv; r.z = az * inv; r.w = aw * inv;
        ((float4*)&rowA[li][0])[q] = r;
        ((float4*)&rowX[li][0])[q] = ((const float4*)(X + (size_t)node * D))[q];
    }
    __syncthreads();
    if (node >= nNodes) return;

    int j = lane;
    float accj = bias[j];
#pragma unroll
    for (int k = 0; k < D; ++k) {
        accj += rowA[li][k] * sWn[k][j] + rowX[li][k] * sWs[k][j];
    }
    h[(size_t)node * D + j] = fmaxf(accj, 0.0f);
}

// ---------------------------------------------------------------------------
// Kernel B: per-node wave over outgoing edges; squared diffs vs in-register
// h[node]; tanh(mean) -> out. off[nNodes+node] indexes vals [E,2E) directly.
// ---------------------------------------------------------------------------
__global__ __launch_bounds__(256) void m_gather(
    const float* __restrict__ h,
    const int* __restrict__ off,              // [2N+1], src section at [N..2N]
    const unsigned short* __restrict__ vals,  // [2E]
    float* __restrict__ out, int nNodes) {
    int t = threadIdx.x;
    int li = t >> 6;
    int lane = t & 63;
    int g = lane >> 4;
    int q = lane & 15;
    int node = blockIdx.x * 4 + li;
    if (node >= nNodes) return;

    float4 hn = ((const float4*)(h + (size_t)node * D))[q];
    int beg = off[nNodes + node];
    int end = off[nNodes + node + 1];

    float ax = 0.f, ay = 0.f, az = 0.f, aw = 0.f;
    int base = beg;
    for (; base + 8 <= end; base += 8) {
        int t0 = vals[base + g];
        int t1 = vals[base + 4 + g];
        float4 u0 = ((const float4*)(h + (size_t)t0 * D))[q];
        float4 u1 = ((const float4*)(h + (size_t)t1 * D))[q];
        float dx0 = hn.x - u0.x, dy0 = hn.y - u0.y, dz0 = hn.z - u0.z, dw0 = hn.w - u0.w;
        float dx1 = hn.x - u1.x, dy1 = hn.y - u1.y, dz1 = hn.z - u1.z, dw1 = hn.w - u1.w;
        ax += dx0 * dx0 + dx1 * dx1; ay += dy0 * dy0 + dy1 * dy1;
        az += dz0 * dz0 + dz1 * dz1; aw += dw0 * dw0 + dw1 * dw1;
    }
    for (; base < end; base += 4) {
        int e = base + g;
        if (e < end) {
            int tt = vals[e];
            float4 u = ((const float4*)(h + (size_t)tt * D))[q];
            float dx = hn.x - u.x, dy = hn.y - u.y, dz = hn.z - u.z, dw = hn.w - u.w;
            ax += dx * dx; ay += dy * dy; az += dz * dz; aw += dw * dw;
        }
    }
#pragma unroll
    for (int o = 16; o <= 32; o <<= 1) {
        ax += __shfl_xor(ax, o); ay += __shfl_xor(ay, o);
        az += __shfl_xor(az, o); aw += __shfl_xor(aw, o);
    }

    if (g == 0) {
        float inv = 1.0f / fmaxf((float)(end - beg), 1.0f);
        float4 r;
        r.x = tanhf(ax * inv); r.y = tanhf(ay * inv);
        r.z = tanhf(az * inv); r.w = tanhf(aw * inv);
        ((float4*)(out + (size_t)node * D))[q] = r;
    }
}

extern "C" void kernel_launch(void* const* d_in, const int* in_sizes, int n_in,
                              void* d_out, int out_size, void* d_ws, size_t ws_size,
                              hipStream_t stream) {
    const float* X  = (const float*)d_in[0];
    const int*   ei = (const int*)d_in[1];   // int32 (JAX canonicalized)
    const float* Wn = (const float*)d_in[2];
    const float* Ws = (const float*)d_in[3];
    const float* b  = (const float*)d_in[4];
    float* out = (float*)d_out;

    int nNodes = in_sizes[0] / D;
    int nEdges = in_sizes[1] / 2;
    const int* src = ei;
    const int* dst = ei + nEdges;

    int n2 = 2 * nNodes;                       // item key space
    int K = (n2 + STEP - 1) / STEP;            // 391 for N=50k (<=1024 req)
    int WGs = (nEdges + PART_CHUNK - 1) / PART_CHUNK;  // 391
    int nCnt = K * WGs;                        // ~153k (<=262k scan cap)
    int nb = (nCnt + SCAN_ELEMS - 1) / SCAN_ELEMS;
    int totalItems = 2 * nEdges;

    // workspace (16B-aligned sections, 4B elems):
    // cnt[K*WGs] | scanned[K*WGs] | bsum[256] | off[2N+1] | part[2E u32]
    // | vals[2E u16] | h[N*D f32]
    size_t o = 0;
    auto align4 = [](size_t x) { return (x + 3) & ~(size_t)3; };
    int* cnt     = (int*)d_ws;                 o = align4((size_t)nCnt);
    int* scanned = (int*)d_ws + o;             o = align4(o + (size_t)nCnt);
    int* bsum    = (int*)d_ws + o;             o = align4(o + 256);
    int* off     = (int*)d_ws + o;             o = align4(o + (size_t)n2 + 1);
    unsigned int* part = (unsigned int*)((int*)d_ws + o);
    o = align4(o + 2 * (size_t)nEdges);
    unsigned short* vals = (unsigned short*)((int*)d_ws + o);
    o = align4(o + (size_t)nEdges);            // 2E u16 == E ints
    float* h = (float*)((int*)d_ws + o);

    part_hist<<<WGs, 256, 0, stream>>>(src, dst, cnt, nEdges, nNodes, K, WGs);
    scan_part<<<nb, 256, 0, stream>>>(cnt, bsum, nCnt);
    scan_tops<<<1, 256, 0, stream>>>(bsum, nb);
    scan_final<<<nb, 256, 0, stream>>>(cnt, bsum, scanned, nCnt);
    part_write<<<WGs, 256, 0, stream>>>(src, dst, scanned, part, nEdges, nNodes, K, WGs);
    csr_build<<<K, STEP, 0, stream>>>(part, scanned, vals, off, n2, K, WGs, totalItems);

    int aBlocks = (nNodes + ANODES - 1) / ANODES;
    agg_gemm<<<aBlocks, 512, 0, stream>>>(X, off, vals, Wn, Ws, b, h, nNodes);
    int mBlocks = (nNodes + 3) / 4;
    m_gather<<<mBlocks, 256, 0, stream>>>(h, off, vals, out, nNodes);
}

// Round 10
// 140.309 us; speedup vs baseline: 1.9261x; 1.0300x over previous
//
#include <hip/hip_runtime.h>
#include <math.h>

#define D 64
#define SCAN_ELEMS 1024    // elements per scan block (256 thr x 4)
#define STEP 256           // nodes per partition bucket (key space 2N)
#define SHIFT 8            // log2(STEP)
#define PART_CHUNK 2048    // edges per partition WG

// Node ids fit u16 (N=50000 < 65536). Partition items are packed u32:
// (key_local_to_bucket << 16) | other_node.
// X and h are staged/stored as bf16 (halves the 205MB/kernel gather traffic).

__device__ inline unsigned short f2bf(float f) {   // round-to-nearest-even
    unsigned u = __float_as_uint(f);
    return (unsigned short)((u + 0x7FFFu + ((u >> 16) & 1u)) >> 16);
}
__device__ inline float bf2f(unsigned short h) {
    return __uint_as_float(((unsigned)h) << 16);
}

// ---------------------------------------------------------------------------
// to_bf16: X (f32) -> Xh (bf16), 8 elems/thread, uint4 stores
// ---------------------------------------------------------------------------
__global__ __launch_bounds__(256) void to_bf16(
    const float* __restrict__ in, unsigned short* __restrict__ outh, int n8) {
    int i = blockIdx.x * blockDim.x + threadIdx.x;
    if (i >= n8) return;
    const float4* p = (const float4*)in + (size_t)i * 2;
    float4 a = p[0], b = p[1];
    union { unsigned short us[8]; uint4 v; } u;
    u.us[0] = f2bf(a.x); u.us[1] = f2bf(a.y); u.us[2] = f2bf(a.z); u.us[3] = f2bf(a.w);
    u.us[4] = f2bf(b.x); u.us[5] = f2bf(b.y); u.us[6] = f2bf(b.z); u.us[7] = f2bf(b.w);
    ((uint4*)outh)[i] = u.v;
}

// ---------------------------------------------------------------------------
// part_hist: per-WG histogram of items into K coarse buckets (LDS counters).
// Each edge contributes 2 items: key=dst (in-CSR) and key=N+src (out-CSR).
// cnt layout bucket-major: cnt[b*WGs + wg].
// ---------------------------------------------------------------------------
__global__ __launch_bounds__(256) void part_hist(
    const int* __restrict__ src, const int* __restrict__ dst,
    int* __restrict__ cnt, int nE, int nN, int K, int WGs) {
    __shared__ int lh[1024];
    int wg = blockIdx.x;
    for (int i = threadIdx.x; i < K; i += 256) lh[i] = 0;
    __syncthreads();
    int base = wg * PART_CHUNK;
    int lim = min(base + PART_CHUNK, nE);
    for (int e = base + threadIdx.x; e < lim; e += 256) {
        int s = src[e], t = dst[e];
        atomicAdd(&lh[t >> SHIFT], 1);
        atomicAdd(&lh[(nN + s) >> SHIFT], 1);
    }
    __syncthreads();
    for (int b = threadIdx.x; b < K; b += 256) cnt[b * WGs + wg] = lh[b];
}

// ---------------------------------------------------------------------------
// scan pass 1: per-block sums
// ---------------------------------------------------------------------------
__global__ __launch_bounds__(256) void scan_part(
    const int* __restrict__ in, int* __restrict__ bsum, int n) {
    __shared__ int sdata[256];
    int b = blockIdx.x, t = threadIdx.x;
    int base = b * SCAN_ELEMS + t * 4;
    int s = 0;
#pragma unroll
    for (int k = 0; k < 4; ++k) { int i = base + k; if (i < n) s += in[i]; }
    sdata[t] = s;
    __syncthreads();
    for (int o = 128; o > 0; o >>= 1) {
        if (t < o) sdata[t] += sdata[t + o];
        __syncthreads();
    }
    if (t == 0) bsum[b] = sdata[0];
}

// ---------------------------------------------------------------------------
// scan pass 2: exclusive scan of block sums in place (nb <= 256)
// ---------------------------------------------------------------------------
__global__ __launch_bounds__(256) void scan_tops(int* __restrict__ bsum, int nb) {
    __shared__ int sd[256];
    int t = threadIdx.x;
    int v = (t < nb) ? bsum[t] : 0;
    sd[t] = v;
    __syncthreads();
    for (int o = 1; o < 256; o <<= 1) {
        int u = (t >= o) ? sd[t - o] : 0;
        __syncthreads();
        sd[t] += u;
        __syncthreads();
    }
    if (t < nb) bsum[t] = sd[t] - v;   // exclusive
}

// ---------------------------------------------------------------------------
// scan pass 3: per-chunk exclusive scan + block offset -> out
// ---------------------------------------------------------------------------
__global__ __launch_bounds__(256) void scan_final(
    const int* __restrict__ in, const int* __restrict__ bsum,
    int* __restrict__ out, int n) {
    __shared__ int sth[256];
    int b = blockIdx.x, t = threadIdx.x;
    int base = b * SCAN_ELEMS + t * 4;
    int v[4]; int s = 0;
#pragma unroll
    for (int k = 0; k < 4; ++k) { int i = base + k; v[k] = (i < n) ? in[i] : 0; s += v[k]; }
    sth[t] = s;
    __syncthreads();
    for (int o = 1; o < 256; o <<= 1) {
        int u = (t >= o) ? sth[t - o] : 0;
        __syncthreads();
        sth[t] += u;
        __syncthreads();
    }
    int run = sth[t] - s + bsum[b];
#pragma unroll
    for (int k = 0; k < 4; ++k) {
        int i = base + k;
        if (i < n) { out[i] = run; run += v[k]; }
    }
}

// ---------------------------------------------------------------------------
// part_write: each WG writes items into ITS OWN contiguous slice of each
// bucket region. Single owner + temporally compact -> writeback ~= payload.
// ---------------------------------------------------------------------------
__global__ __launch_bounds__(256) void part_write(
    const int* __restrict__ src, const int* __restrict__ dst,
    const int* __restrict__ scanned, unsigned int* __restrict__ part,
    int nE, int nN, int K, int WGs) {
    __shared__ int cur[1024];
    int wg = blockIdx.x;
    for (int b = threadIdx.x; b < K; b += 256) cur[b] = scanned[b * WGs + wg];
    __syncthreads();
    int base = wg * PART_CHUNK;
    int lim = min(base + PART_CHUNK, nE);
    for (int e = base + threadIdx.x; e < lim; e += 256) {
        int s = src[e], t = dst[e];
        int k1 = t;
        int p1 = atomicAdd(&cur[k1 >> SHIFT], 1);
        part[p1] = ((unsigned)(k1 & (STEP - 1)) << 16) | (unsigned)s;
        int k2 = nN + s;
        int p2 = atomicAdd(&cur[k2 >> SHIFT], 1);
        part[p2] = ((unsigned)(k2 & (STEP - 1)) << 16) | (unsigned)t;
    }
}

// ---------------------------------------------------------------------------
// csr_build: one WG per bucket. LDS degree count + prefix -> off[] exact,
// then scatter u16 vals into the WG-private region.
// ---------------------------------------------------------------------------
__global__ __launch_bounds__(256) void csr_build(
    const unsigned int* __restrict__ part, const int* __restrict__ scanned,
    unsigned short* __restrict__ vals, int* __restrict__ off,
    int n2, int K, int WGs, int totalItems) {
    __shared__ int deg[STEP];
    __shared__ int pfx[STEP];
    int b = blockIdx.x, t = threadIdx.x;
    int base = scanned[b * WGs];
    int endi = (b + 1 < K) ? scanned[(b + 1) * WGs] : totalItems;

    deg[t] = 0;
    __syncthreads();
    for (int i = base + t; i < endi; i += 256)
        atomicAdd(&deg[part[i] >> 16], 1);
    __syncthreads();

    pfx[t] = deg[t];
    __syncthreads();
    for (int o = 1; o < STEP; o <<= 1) {
        int u = (t >= o) ? pfx[t - o] : 0;
        __syncthreads();
        pfx[t] += u;
        __syncthreads();
    }
    int ex = pfx[t] - deg[t];
    int g = b * STEP + t;
    if (g < n2) off[g] = base + ex;
    if (b == K - 1 && t == 0) off[n2] = totalItems;
    deg[t] = ex;           // reuse as bucket-local cursor
    __syncthreads();

    for (int i = base + t; i < endi; i += 256) {
        unsigned u = part[i];
        int l = (int)(u >> 16);
        int p = atomicAdd(&deg[l], 1);
        vals[base + p] = (unsigned short)(u & 0xffffu);
    }
}

// ---------------------------------------------------------------------------
// Kernel A: 512-thread blocks = 8 node-waves sharing one W staging (LDS
// 36864B -> 4 blocks/CU -> 32 waves/CU). Per wave: 4 lane-groups of 16
// gather bf16 X rows (ushort4 = 8B/lane, 128B/row), 16 edges in flight,
// butterfly-reduce, then fused dual 64x64 GEMM+bias+ReLU -> bf16 h.
// ---------------------------------------------------------------------------
#define ANODES 8
__global__ __launch_bounds__(512) void agg_gemm(
    const unsigned short* __restrict__ Xh,    // [N*D] bf16
    const int* __restrict__ off,              // [2N+1]
    const unsigned short* __restrict__ vals,  // [2E]
    const float* __restrict__ Wn, const float* __restrict__ Ws,
    const float* __restrict__ bias,
    unsigned short* __restrict__ hh, int nNodes) {
    __shared__ float sWn[D][D];
    __shared__ float sWs[D][D];
    __shared__ float rowA[ANODES][D];
    __shared__ float rowX[ANODES][D];

    int t = threadIdx.x;
    for (int i = t; i < D * D; i += 512) {
        sWn[i >> 6][i & 63] = Wn[i];
        sWs[i >> 6][i & 63] = Ws[i];
    }

    int li = t >> 6;       // wave id = local node 0..7
    int lane = t & 63;
    int g = lane >> 4;     // edge group 0..3
    int q = lane & 15;     // ushort4 index: dims 4q..4q+3
    int node = blockIdx.x * ANODES + li;

    float ax = 0.f, ay = 0.f, az = 0.f, aw = 0.f;
    int beg = 0, end = 0;
    if (node < nNodes) { beg = off[node]; end = off[node + 1]; }

    int base = beg;
    for (; base + 16 <= end; base += 16) {
        int s0 = vals[base + g];
        int s1 = vals[base + 4 + g];
        int s2 = vals[base + 8 + g];
        int s3 = vals[base + 12 + g];
        ushort4 v0 = ((const ushort4*)(Xh + (size_t)s0 * D))[q];
        ushort4 v1 = ((const ushort4*)(Xh + (size_t)s1 * D))[q];
        ushort4 v2 = ((const ushort4*)(Xh + (size_t)s2 * D))[q];
        ushort4 v3 = ((const ushort4*)(Xh + (size_t)s3 * D))[q];
        ax += bf2f(v0.x) + bf2f(v1.x) + bf2f(v2.x) + bf2f(v3.x);
        ay += bf2f(v0.y) + bf2f(v1.y) + bf2f(v2.y) + bf2f(v3.y);
        az += bf2f(v0.z) + bf2f(v1.z) + bf2f(v2.z) + bf2f(v3.z);
        aw += bf2f(v0.w) + bf2f(v1.w) + bf2f(v2.w) + bf2f(v3.w);
    }
    for (; base < end; base += 4) {
        int e = base + g;
        if (e < end) {
            int s = vals[e];
            ushort4 v = ((const ushort4*)(Xh + (size_t)s * D))[q];
            ax += bf2f(v.x); ay += bf2f(v.y); az += bf2f(v.z); aw += bf2f(v.w);
        }
    }
    // reduce across the 4 edge-groups (lanes differing in bits 4,5)
#pragma unroll
    for (int o = 16; o <= 32; o <<= 1) {
        ax += __shfl_xor(ax, o); ay += __shfl_xor(ay, o);
        az += __shfl_xor(az, o); aw += __shfl_xor(aw, o);
    }

    if (node < nNodes && g == 0) {
        float inv = 1.0f / fmaxf((float)(end - beg), 1.0f);
        float4 r; r.x = ax * inv; r.y = ay * inv; r.z = az * inv; r.w = aw * inv;
        ((float4*)&rowA[li][0])[q] = r;
        ushort4 xv = ((const ushort4*)(Xh + (size_t)node * D))[q];
        float4 xr; xr.x = bf2f(xv.x); xr.y = bf2f(xv.y);
        xr.z = bf2f(xv.z); xr.w = bf2f(xv.w);
        ((float4*)&rowX[li][0])[q] = xr;
    }
    __syncthreads();
    if (node >= nNodes) return;

    int j = lane;
    float accj = bias[j];
#pragma unroll
    for (int k = 0; k < D; ++k) {
        accj += rowA[li][k] * sWn[k][j] + rowX[li][k] * sWs[k][j];
    }
    hh[(size_t)node * D + j] = f2bf(fmaxf(accj, 0.0f));
}

// ---------------------------------------------------------------------------
// Kernel B: per-node wave over outgoing edges; bf16 h gather (8B/lane),
// squared diffs in f32 vs in-register hn; tanh(mean) -> f32 out.
// off[nNodes+node] indexes vals [E,2E) directly.
// ---------------------------------------------------------------------------
__global__ __launch_bounds__(256) void m_gather(
    const unsigned short* __restrict__ hh,    // [N*D] bf16
    const int* __restrict__ off,              // [2N+1], src section at [N..2N]
    const unsigned short* __restrict__ vals,  // [2E]
    float* __restrict__ out, int nNodes) {
    int t = threadIdx.x;
    int li = t >> 6;
    int lane = t & 63;
    int g = lane >> 4;
    int q = lane & 15;
    int node = blockIdx.x * 4 + li;
    if (node >= nNodes) return;

    ushort4 hv = ((const ushort4*)(hh + (size_t)node * D))[q];
    float hx = bf2f(hv.x), hy = bf2f(hv.y), hz = bf2f(hv.z), hw = bf2f(hv.w);
    int beg = off[nNodes + node];
    int end = off[nNodes + node + 1];

    float ax = 0.f, ay = 0.f, az = 0.f, aw = 0.f;
    int base = beg;
    for (; base + 16 <= end; base += 16) {
        int t0 = vals[base + g];
        int t1 = vals[base + 4 + g];
        int t2 = vals[base + 8 + g];
        int t3 = vals[base + 12 + g];
        ushort4 u0 = ((const ushort4*)(hh + (size_t)t0 * D))[q];
        ushort4 u1 = ((const ushort4*)(hh + (size_t)t1 * D))[q];
        ushort4 u2 = ((const ushort4*)(hh + (size_t)t2 * D))[q];
        ushort4 u3 = ((const ushort4*)(hh + (size_t)t3 * D))[q];
        float d0, d1, d2, d3;
        d0 = hx - bf2f(u0.x); d1 = hx - bf2f(u1.x); d2 = hx - bf2f(u2.x); d3 = hx - bf2f(u3.x);
        ax += d0 * d0 + d1 * d1 + d2 * d2 + d3 * d3;
        d0 = hy - bf2f(u0.y); d1 = hy - bf2f(u1.y); d2 = hy - bf2f(u2.y); d3 = hy - bf2f(u3.y);
        ay += d0 * d0 + d1 * d1 + d2 * d2 + d3 * d3;
        d0 = hz - bf2f(u0.z); d1 = hz - bf2f(u1.z); d2 = hz - bf2f(u2.z); d3 = hz - bf2f(u3.z);
        az += d0 * d0 + d1 * d1 + d2 * d2 + d3 * d3;
        d0 = hw - bf2f(u0.w); d1 = hw - bf2f(u1.w); d2 = hw - bf2f(u2.w); d3 = hw - bf2f(u3.w);
        aw += d0 * d0 + d1 * d1 + d2 * d2 + d3 * d3;
    }
    for (; base < end; base += 4) {
        int e = base + g;
        if (e < end) {
            int tt = vals[e];
            ushort4 u = ((const ushort4*)(hh + (size_t)tt * D))[q];
            float dx = hx - bf2f(u.x), dy = hy - bf2f(u.y);
            float dz = hz - bf2f(u.z), dw = hw - bf2f(u.w);
            ax += dx * dx; ay += dy * dy; az += dz * dz; aw += dw * dw;
        }
    }
#pragma unroll
    for (int o = 16; o <= 32; o <<= 1) {
        ax += __shfl_xor(ax, o); ay += __shfl_xor(ay, o);
        az += __shfl_xor(az, o); aw += __shfl_xor(aw, o);
    }

    if (g == 0) {
        float inv = 1.0f / fmaxf((float)(end - beg), 1.0f);
        float4 r;
        r.x = tanhf(ax * inv); r.y = tanhf(ay * inv);
        r.z = tanhf(az * inv); r.w = tanhf(aw * inv);
        ((float4*)(out + (size_t)node * D))[q] = r;
    }
}

extern "C" void kernel_launch(void* const* d_in, const int* in_sizes, int n_in,
                              void* d_out, int out_size, void* d_ws, size_t ws_size,
                              hipStream_t stream) {
    const float* X  = (const float*)d_in[0];
    const int*   ei = (const int*)d_in[1];   // int32 (JAX canonicalized)
    const float* Wn = (const float*)d_in[2];
    const float* Ws = (const float*)d_in[3];
    const float* b  = (const float*)d_in[4];
    float* out = (float*)d_out;

    int nNodes = in_sizes[0] / D;
    int nEdges = in_sizes[1] / 2;
    const int* src = ei;
    const int* dst = ei + nEdges;

    int n2 = 2 * nNodes;                       // item key space
    int K = (n2 + STEP - 1) / STEP;            // 391 for N=50k
    int WGs = (nEdges + PART_CHUNK - 1) / PART_CHUNK;  // 391
    int nCnt = K * WGs;
    int nb = (nCnt + SCAN_ELEMS - 1) / SCAN_ELEMS;
    int totalItems = 2 * nEdges;

    // workspace (16B-aligned sections, 4B elems):
    // cnt[K*WGs] | scanned[K*WGs] | bsum[256] | off[2N+1] | part[2E u32]
    // | vals[2E u16] | Xh[N*D u16] | hh[N*D u16]
    size_t o = 0;
    auto align4 = [](size_t x) { return (x + 3) & ~(size_t)3; };
    int* cnt     = (int*)d_ws;                 o = align4((size_t)nCnt);
    int* scanned = (int*)d_ws + o;             o = align4(o + (size_t)nCnt);
    int* bsum    = (int*)d_ws + o;             o = align4(o + 256);
    int* off     = (int*)d_ws + o;             o = align4(o + (size_t)n2 + 1);
    unsigned int* part = (unsigned int*)((int*)d_ws + o);
    o = align4(o + 2 * (size_t)nEdges);
    unsigned short* vals = (unsigned short*)((int*)d_ws + o);
    o = align4(o + (size_t)nEdges);            // 2E u16 == E ints
    unsigned short* Xh = (unsigned short*)((int*)d_ws + o);
    o = align4(o + (size_t)nNodes * D / 2);    // N*D u16
    unsigned short* hh = (unsigned short*)((int*)d_ws + o);

    int n8 = nNodes * D / 8;
    to_bf16<<<(n8 + 255) / 256, 256, 0, stream>>>(X, Xh, n8);

    part_hist<<<WGs, 256, 0, stream>>>(src, dst, cnt, nEdges, nNodes, K, WGs);
    scan_part<<<nb, 256, 0, stream>>>(cnt, bsum, nCnt);
    scan_tops<<<1, 256, 0, stream>>>(bsum, nb);
    scan_final<<<nb, 256, 0, stream>>>(cnt, bsum, scanned, nCnt);
    part_write<<<WGs, 256, 0, stream>>>(src, dst, scanned, part, nEdges, nNodes, K, WGs);
    csr_build<<<K, STEP, 0, stream>>>(part, scanned, vals, off, n2, K, WGs, totalItems);

    int aBlocks = (nNodes + ANODES - 1) / ANODES;
    agg_gemm<<<aBlocks, 512, 0, stream>>>(Xh, off, vals, Wn, Ws, b, hh, nNodes);
    int mBlocks = (nNodes + 3) / 4;
    m_gather<<<mBlocks, 256, 0, stream>>>(hh, off, vals, out, nNodes);
}

// Round 11
// 118.224 us; speedup vs baseline: 2.2859x; 1.1868x over previous
//
#include <hip/hip_runtime.h>
#include <math.h>

#define D 64
#define SCAN_ELEMS 1024    // elements per scan block (256 thr x 4)
#define STEP 256           // nodes per partition bucket (key space 2N)
#define SHIFT 8            // log2(STEP)
#define PART_CHUNK 2048    // edges per partition WG

// Node ids fit u16 (N=50000 < 65536). Partition items are packed u32:
// (key_local_to_bucket << 16) | other_node.
// X, h, Wn, Ws are staged as bf16. GEMM runs on MFMA (16x16x32 bf16).

typedef __attribute__((ext_vector_type(8))) short bf16x8;
typedef __attribute__((ext_vector_type(4))) float f32x4;

__device__ inline unsigned short f2bf(float f) {   // round-to-nearest-even
    unsigned u = __float_as_uint(f);
    return (unsigned short)((u + 0x7FFFu + ((u >> 16) & 1u)) >> 16);
}
__device__ inline float bf2f(unsigned short h) {
    return __uint_as_float(((unsigned)h) << 16);
}

// ---------------------------------------------------------------------------
// to_bf16: f32 -> bf16, 8 elems/thread, uint4 stores
// ---------------------------------------------------------------------------
__global__ __launch_bounds__(256) void to_bf16(
    const float* __restrict__ in, unsigned short* __restrict__ outh, int n8) {
    int i = blockIdx.x * blockDim.x + threadIdx.x;
    if (i >= n8) return;
    const float4* p = (const float4*)in + (size_t)i * 2;
    float4 a = p[0], b = p[1];
    union { unsigned short us[8]; uint4 v; } u;
    u.us[0] = f2bf(a.x); u.us[1] = f2bf(a.y); u.us[2] = f2bf(a.z); u.us[3] = f2bf(a.w);
    u.us[4] = f2bf(b.x); u.us[5] = f2bf(b.y); u.us[6] = f2bf(b.z); u.us[7] = f2bf(b.w);
    ((uint4*)outh)[i] = u.v;
}

// ---------------------------------------------------------------------------
// part_hist: per-WG histogram of items into K coarse buckets (LDS counters).
// ---------------------------------------------------------------------------
__global__ __launch_bounds__(256) void part_hist(
    const int* __restrict__ src, const int* __restrict__ dst,
    int* __restrict__ cnt, int nE, int nN, int K, int WGs) {
    __shared__ int lh[1024];
    int wg = blockIdx.x;
    for (int i = threadIdx.x; i < K; i += 256) lh[i] = 0;
    __syncthreads();
    int base = wg * PART_CHUNK;
    int lim = min(base + PART_CHUNK, nE);
    for (int e = base + threadIdx.x; e < lim; e += 256) {
        int s = src[e], t = dst[e];
        atomicAdd(&lh[t >> SHIFT], 1);
        atomicAdd(&lh[(nN + s) >> SHIFT], 1);
    }
    __syncthreads();
    for (int b = threadIdx.x; b < K; b += 256) cnt[b * WGs + wg] = lh[b];
}

// ---------------------------------------------------------------------------
// scan pass 1: per-block sums
// ---------------------------------------------------------------------------
__global__ __launch_bounds__(256) void scan_part(
    const int* __restrict__ in, int* __restrict__ bsum, int n) {
    __shared__ int sdata[256];
    int b = blockIdx.x, t = threadIdx.x;
    int base = b * SCAN_ELEMS + t * 4;
    int s = 0;
#pragma unroll
    for (int k = 0; k < 4; ++k) { int i = base + k; if (i < n) s += in[i]; }
    sdata[t] = s;
    __syncthreads();
    for (int o = 128; o > 0; o >>= 1) {
        if (t < o) sdata[t] += sdata[t + o];
        __syncthreads();
    }
    if (t == 0) bsum[b] = sdata[0];
}

// ---------------------------------------------------------------------------
// scan pass 2: exclusive scan of block sums in place (nb <= 256)
// ---------------------------------------------------------------------------
__global__ __launch_bounds__(256) void scan_tops(int* __restrict__ bsum, int nb) {
    __shared__ int sd[256];
    int t = threadIdx.x;
    int v = (t < nb) ? bsum[t] : 0;
    sd[t] = v;
    __syncthreads();
    for (int o = 1; o < 256; o <<= 1) {
        int u = (t >= o) ? sd[t - o] : 0;
        __syncthreads();
        sd[t] += u;
        __syncthreads();
    }
    if (t < nb) bsum[t] = sd[t] - v;   // exclusive
}

// ---------------------------------------------------------------------------
// scan pass 3: per-chunk exclusive scan + block offset -> out
// ---------------------------------------------------------------------------
__global__ __launch_bounds__(256) void scan_final(
    const int* __restrict__ in, const int* __restrict__ bsum,
    int* __restrict__ out, int n) {
    __shared__ int sth[256];
    int b = blockIdx.x, t = threadIdx.x;
    int base = b * SCAN_ELEMS + t * 4;
    int v[4]; int s = 0;
#pragma unroll
    for (int k = 0; k < 4; ++k) { int i = base + k; v[k] = (i < n) ? in[i] : 0; s += v[k]; }
    sth[t] = s;
    __syncthreads();
    for (int o = 1; o < 256; o <<= 1) {
        int u = (t >= o) ? sth[t - o] : 0;
        __syncthreads();
        sth[t] += u;
        __syncthreads();
    }
    int run = sth[t] - s + bsum[b];
#pragma unroll
    for (int k = 0; k < 4; ++k) {
        int i = base + k;
        if (i < n) { out[i] = run; run += v[k]; }
    }
}

// ---------------------------------------------------------------------------
// part_write: each WG writes items into ITS OWN contiguous slice of each
// bucket region. Single owner + temporally compact -> writeback ~= payload.
// ---------------------------------------------------------------------------
__global__ __launch_bounds__(256) void part_write(
    const int* __restrict__ src, const int* __restrict__ dst,
    const int* __restrict__ scanned, unsigned int* __restrict__ part,
    int nE, int nN, int K, int WGs) {
    __shared__ int cur[1024];
    int wg = blockIdx.x;
    for (int b = threadIdx.x; b < K; b += 256) cur[b] = scanned[b * WGs + wg];
    __syncthreads();
    int base = wg * PART_CHUNK;
    int lim = min(base + PART_CHUNK, nE);
    for (int e = base + threadIdx.x; e < lim; e += 256) {
        int s = src[e], t = dst[e];
        int k1 = t;
        int p1 = atomicAdd(&cur[k1 >> SHIFT], 1);
        part[p1] = ((unsigned)(k1 & (STEP - 1)) << 16) | (unsigned)s;
        int k2 = nN + s;
        int p2 = atomicAdd(&cur[k2 >> SHIFT], 1);
        part[p2] = ((unsigned)(k2 & (STEP - 1)) << 16) | (unsigned)t;
    }
}

// ---------------------------------------------------------------------------
// csr_build: one WG per bucket. LDS degree count + prefix -> off[] exact,
// then scatter u16 vals into the WG-private region.
// ---------------------------------------------------------------------------
__global__ __launch_bounds__(256) void csr_build(
    const unsigned int* __restrict__ part, const int* __restrict__ scanned,
    unsigned short* __restrict__ vals, int* __restrict__ off,
    int n2, int K, int WGs, int totalItems) {
    __shared__ int deg[STEP];
    __shared__ int pfx[STEP];
    int b = blockIdx.x, t = threadIdx.x;
    int base = scanned[b * WGs];
    int endi = (b + 1 < K) ? scanned[(b + 1) * WGs] : totalItems;

    deg[t] = 0;
    __syncthreads();
    for (int i = base + t; i < endi; i += 256)
        atomicAdd(&deg[part[i] >> 16], 1);
    __syncthreads();

    pfx[t] = deg[t];
    __syncthreads();
    for (int o = 1; o < STEP; o <<= 1) {
        int u = (t >= o) ? pfx[t - o] : 0;
        __syncthreads();
        pfx[t] += u;
        __syncthreads();
    }
    int ex = pfx[t] - deg[t];
    int g = b * STEP + t;
    if (g < n2) off[g] = base + ex;
    if (b == K - 1 && t == 0) off[n2] = totalItems;
    deg[t] = ex;           // reuse as bucket-local cursor
    __syncthreads();

    for (int i = base + t; i < endi; i += 256) {
        unsigned u = part[i];
        int l = (int)(u >> 16);
        int p = atomicAdd(&deg[l], 1);
        vals[base + p] = (unsigned short)(u & 0xffffu);
    }
}

// ---------------------------------------------------------------------------
// Kernel A: 512 thr = 8 node-waves. Gather phase unchanged (4x16 groups,
// 16 edges in flight, bf16 rows). Then rowA/rowX staged to a tiny padded
// bf16 LDS buffer (rows 8..15 zero) and waves 0-3 each compute one 16-col
// tile of H = relu(Aagg@Wn + Ax@Ws + b) via 4x mfma_f32_16x16x32_bf16.
// B-fragments come straight from global bf16 W (L1-hot) — no W LDS at all.
// A and B fragments use the SAME k-packing convention, so any HW
// k-within-lane-group ordering cancels in the dot product.
// LDS = 2*16*72*2B = 4608B (was 36864) -> wave-cap occupancy (32/CU).
// ---------------------------------------------------------------------------
#define ANODES 8
#define ROWB 144   // row stride in bytes: 72 u16 (64 data + 8 pad)
__global__ __launch_bounds__(512) void agg_gemm(
    const unsigned short* __restrict__ Xh,    // [N*D] bf16
    const int* __restrict__ off,              // [2N+1]
    const unsigned short* __restrict__ vals,  // [2E]
    const unsigned short* __restrict__ Whn,   // [64*64] bf16
    const unsigned short* __restrict__ Whs,   // [64*64] bf16
    const float* __restrict__ bias,
    unsigned short* __restrict__ hh, int nNodes) {
    __shared__ __align__(16) unsigned short rows[2][16][72];

    int t = threadIdx.x;
    // zero pad rows 8..15 of both buffers (2 x 8 x 144B = 2304B)
    if (t < 288) {
        int b = t / 144, r = t - b * 144;
        *(unsigned long long*)((char*)&rows[b][8][0] + r * 8) = 0ULL;
    }

    int li = t >> 6;       // wave id = local node 0..7
    int lane = t & 63;
    int g = lane >> 4;     // edge group 0..3
    int q = lane & 15;     // ushort4 index: dims 4q..4q+3
    int bb = blockIdx.x * ANODES;
    int node = bb + li;

    float ax = 0.f, ay = 0.f, az = 0.f, aw = 0.f;
    int beg = 0, end = 0;
    if (node < nNodes) { beg = off[node]; end = off[node + 1]; }

    int base = beg;
    for (; base + 16 <= end; base += 16) {
        int s0 = vals[base + g];
        int s1 = vals[base + 4 + g];
        int s2 = vals[base + 8 + g];
        int s3 = vals[base + 12 + g];
        ushort4 v0 = ((const ushort4*)(Xh + (size_t)s0 * D))[q];
        ushort4 v1 = ((const ushort4*)(Xh + (size_t)s1 * D))[q];
        ushort4 v2 = ((const ushort4*)(Xh + (size_t)s2 * D))[q];
        ushort4 v3 = ((const ushort4*)(Xh + (size_t)s3 * D))[q];
        ax += bf2f(v0.x) + bf2f(v1.x) + bf2f(v2.x) + bf2f(v3.x);
        ay += bf2f(v0.y) + bf2f(v1.y) + bf2f(v2.y) + bf2f(v3.y);
        az += bf2f(v0.z) + bf2f(v1.z) + bf2f(v2.z) + bf2f(v3.z);
        aw += bf2f(v0.w) + bf2f(v1.w) + bf2f(v2.w) + bf2f(v3.w);
    }
    for (; base < end; base += 4) {
        int e = base + g;
        if (e < end) {
            int s = vals[e];
            ushort4 v = ((const ushort4*)(Xh + (size_t)s * D))[q];
            ax += bf2f(v.x); ay += bf2f(v.y); az += bf2f(v.z); aw += bf2f(v.w);
        }
    }
#pragma unroll
    for (int o = 16; o <= 32; o <<= 1) {
        ax += __shfl_xor(ax, o); ay += __shfl_xor(ay, o);
        az += __shfl_xor(az, o); aw += __shfl_xor(aw, o);
    }

    if (node < nNodes && g == 0) {
        float inv = 1.0f / fmaxf((float)(end - beg), 1.0f);
        ushort4 mv;
        mv.x = f2bf(ax * inv); mv.y = f2bf(ay * inv);
        mv.z = f2bf(az * inv); mv.w = f2bf(aw * inv);
        *(ushort4*)((char*)&rows[0][li][0] + q * 8) = mv;
        ushort4 xv = ((const ushort4*)(Xh + (size_t)node * D))[q];
        *(ushort4*)((char*)&rows[1][li][0] + q * 8) = xv;
    }
    __syncthreads();

    // ---- MFMA GEMM: waves 0..3, wave li owns N-tile li (cols li*16..+15) --
    if (li >= 4) return;
    int c = lane & 15;     // A row index / B+C col index
    int hi = lane >> 4;    // k-group / C row-group
    f32x4 acc;
    float bv = bias[li * 16 + c];
    acc[0] = bv; acc[1] = bv; acc[2] = bv; acc[3] = bv;
#pragma unroll
    for (int kh = 0; kh < 2; ++kh) {
        bf16x8 aA = *(const bf16x8*)((const char*)&rows[0][0][0] + c * ROWB + kh * 64 + hi * 16);
        bf16x8 aX = *(const bf16x8*)((const char*)&rows[1][0][0] + c * ROWB + kh * 64 + hi * 16);
        bf16x8 bN, bS;
        int kb = kh * 32 + hi * 8;
#pragma unroll
        for (int j = 0; j < 8; ++j) {
            bN[j] = (short)Whn[(size_t)(kb + j) * D + li * 16 + c];
            bS[j] = (short)Whs[(size_t)(kb + j) * D + li * 16 + c];
        }
        acc = __builtin_amdgcn_mfma_f32_16x16x32_bf16(aA, bN, acc, 0, 0, 0);
        acc = __builtin_amdgcn_mfma_f32_16x16x32_bf16(aX, bS, acc, 0, 0, 0);
    }
    // C/D layout (m89-verified): col = lane&15, row = (lane>>4)*4 + reg
#pragma unroll
    for (int r = 0; r < 4; ++r) {
        int row = hi * 4 + r;
        if (row < 8) {
            int n2a = bb + row;
            if (n2a < nNodes)
                hh[(size_t)n2a * D + li * 16 + c] = f2bf(fmaxf(acc[r], 0.0f));
        }
    }
}

// ---------------------------------------------------------------------------
// Kernel B: per-node wave over outgoing edges; bf16 h gather (8B/lane),
// squared diffs in f32; tanh(mean) -> f32 out. off[nNodes+node] indexes
// vals [E,2E) directly.
// ---------------------------------------------------------------------------
__global__ __launch_bounds__(256) void m_gather(
    const unsigned short* __restrict__ hh,    // [N*D] bf16
    const int* __restrict__ off,              // [2N+1], src section at [N..2N]
    const unsigned short* __restrict__ vals,  // [2E]
    float* __restrict__ out, int nNodes) {
    int t = threadIdx.x;
    int li = t >> 6;
    int lane = t & 63;
    int g = lane >> 4;
    int q = lane & 15;
    int node = blockIdx.x * 4 + li;
    if (node >= nNodes) return;

    ushort4 hv = ((const ushort4*)(hh + (size_t)node * D))[q];
    float hx = bf2f(hv.x), hy = bf2f(hv.y), hz = bf2f(hv.z), hw = bf2f(hv.w);
    int beg = off[nNodes + node];
    int end = off[nNodes + node + 1];

    float ax = 0.f, ay = 0.f, az = 0.f, aw = 0.f;
    int base = beg;
    for (; base + 16 <= end; base += 16) {
        int t0 = vals[base + g];
        int t1 = vals[base + 4 + g];
        int t2 = vals[base + 8 + g];
        int t3 = vals[base + 12 + g];
        ushort4 u0 = ((const ushort4*)(hh + (size_t)t0 * D))[q];
        ushort4 u1 = ((const ushort4*)(hh + (size_t)t1 * D))[q];
        ushort4 u2 = ((const ushort4*)(hh + (size_t)t2 * D))[q];
        ushort4 u3 = ((const ushort4*)(hh + (size_t)t3 * D))[q];
        float d0, d1, d2, d3;
        d0 = hx - bf2f(u0.x); d1 = hx - bf2f(u1.x); d2 = hx - bf2f(u2.x); d3 = hx - bf2f(u3.x);
        ax += d0 * d0 + d1 * d1 + d2 * d2 + d3 * d3;
        d0 = hy - bf2f(u0.y); d1 = hy - bf2f(u1.y); d2 = hy - bf2f(u2.y); d3 = hy - bf2f(u3.y);
        ay += d0 * d0 + d1 * d1 + d2 * d2 + d3 * d3;
        d0 = hz - bf2f(u0.z); d1 = hz - bf2f(u1.z); d2 = hz - bf2f(u2.z); d3 = hz - bf2f(u3.z);
        az += d0 * d0 + d1 * d1 + d2 * d2 + d3 * d3;
        d0 = hw - bf2f(u0.w); d1 = hw - bf2f(u1.w); d2 = hw - bf2f(u2.w); d3 = hw - bf2f(u3.w);
        aw += d0 * d0 + d1 * d1 + d2 * d2 + d3 * d3;
    }
    for (; base < end; base += 4) {
        int e = base + g;
        if (e < end) {
            int tt = vals[e];
            ushort4 u = ((const ushort4*)(hh + (size_t)tt * D))[q];
            float dx = hx - bf2f(u.x), dy = hy - bf2f(u.y);
            float dz = hz - bf2f(u.z), dw = hw - bf2f(u.w);
            ax += dx * dx; ay += dy * dy; az += dz * dz; aw += dw * dw;
        }
    }
#pragma unroll
    for (int o = 16; o <= 32; o <<= 1) {
        ax += __shfl_xor(ax, o); ay += __shfl_xor(ay, o);
        az += __shfl_xor(az, o); aw += __shfl_xor(aw, o);
    }

    if (g == 0) {
        float inv = 1.0f / fmaxf((float)(end - beg), 1.0f);
        float4 r;
        r.x = tanhf(ax * inv); r.y = tanhf(ay * inv);
        r.z = tanhf(az * inv); r.w = tanhf(aw * inv);
        ((float4*)(out + (size_t)node * D))[q] = r;
    }
}

extern "C" void kernel_launch(void* const* d_in, const int* in_sizes, int n_in,
                              void* d_out, int out_size, void* d_ws, size_t ws_size,
                              hipStream_t stream) {
    const float* X  = (const float*)d_in[0];
    const int*   ei = (const int*)d_in[1];   // int32 (JAX canonicalized)
    const float* Wn = (const float*)d_in[2];
    const float* Ws = (const float*)d_in[3];
    const float* b  = (const float*)d_in[4];
    float* out = (float*)d_out;

    int nNodes = in_sizes[0] / D;
    int nEdges = in_sizes[1] / 2;
    const int* src = ei;
    const int* dst = ei + nEdges;

    int n2 = 2 * nNodes;                       // item key space
    int K = (n2 + STEP - 1) / STEP;            // 391 for N=50k
    int WGs = (nEdges + PART_CHUNK - 1) / PART_CHUNK;  // 391
    int nCnt = K * WGs;
    int nb = (nCnt + SCAN_ELEMS - 1) / SCAN_ELEMS;
    int totalItems = 2 * nEdges;

    // workspace (16B-aligned sections, 4B elems):
    // cnt[K*WGs] | scanned[K*WGs] | bsum[256] | off[2N+1] | part[2E u32]
    // | vals[2E u16] | Xh[N*D u16] | hh[N*D u16] | Whn[4096 u16] | Whs[...]
    size_t o = 0;
    auto align4 = [](size_t x) { return (x + 3) & ~(size_t)3; };
    int* cnt     = (int*)d_ws;                 o = align4((size_t)nCnt);
    int* scanned = (int*)d_ws + o;             o = align4(o + (size_t)nCnt);
    int* bsum    = (int*)d_ws + o;             o = align4(o + 256);
    int* off     = (int*)d_ws + o;             o = align4(o + (size_t)n2 + 1);
    unsigned int* part = (unsigned int*)((int*)d_ws + o);
    o = align4(o + 2 * (size_t)nEdges);
    unsigned short* vals = (unsigned short*)((int*)d_ws + o);
    o = align4(o + (size_t)nEdges);            // 2E u16 == E ints
    unsigned short* Xh = (unsigned short*)((int*)d_ws + o);
    o = align4(o + (size_t)nNodes * D / 2);    // N*D u16
    unsigned short* hh = (unsigned short*)((int*)d_ws + o);
    o = align4(o + (size_t)nNodes * D / 2);
    unsigned short* Whn = (unsigned short*)((int*)d_ws + o);
    o = align4(o + (size_t)(D * D) / 2);
    unsigned short* Whs = (unsigned short*)((int*)d_ws + o);

    int n8 = nNodes * D / 8;
    to_bf16<<<(n8 + 255) / 256, 256, 0, stream>>>(X, Xh, n8);
    to_bf16<<<2, 256, 0, stream>>>(Wn, Whn, D * D / 8);
    to_bf16<<<2, 256, 0, stream>>>(Ws, Whs, D * D / 8);

    part_hist<<<WGs, 256, 0, stream>>>(src, dst, cnt, nEdges, nNodes, K, WGs);
    scan_part<<<nb, 256, 0, stream>>>(cnt, bsum, nCnt);
    scan_tops<<<1, 256, 0, stream>>>(bsum, nb);
    scan_final<<<nb, 256, 0, stream>>>(cnt, bsum, scanned, nCnt);
    part_write<<<WGs, 256, 0, stream>>>(src, dst, scanned, part, nEdges, nNodes, K, WGs);
    csr_build<<<K, STEP, 0, stream>>>(part, scanned, vals, off, n2, K, WGs, totalItems);

    int aBlocks = (nNodes + ANODES - 1) / ANODES;
    agg_gemm<<<aBlocks, 512, 0, stream>>>(Xh, off, vals, Whn, Whs, b, hh, nNodes);
    int mBlocks = (nNodes + 3) / 4;
    m_gather<<<mBlocks, 256, 0, stream>>>(hh, off, vals, out, nNodes);
}

// Round 12
// 116.050 us; speedup vs baseline: 2.3287x; 1.0187x over previous
//
#include <hip/hip_runtime.h>
#include <math.h>

#define D 64
#define SCAN_ELEMS 1024    // elements per scan block (256 thr x 4)
#define STEP 256           // nodes per partition bucket (key space 2N)
#define SHIFT 8            // log2(STEP)
#define PART_CHUNK 2048    // edges per partition WG

// Node ids fit u16 (N=50000 < 65536). Partition items are packed u32:
// (key_local_to_bucket << 16) | other_node.
// X, h, Wn, Ws staged as bf16. GEMM on MFMA (16x16x32 bf16).
// Gathers: 8 lane-groups x 8 lanes, ushort8 (16B/lane) = 1KB/wave/instr.

typedef __attribute__((ext_vector_type(8))) short bf16x8;
typedef __attribute__((ext_vector_type(8))) unsigned short u16x8;
typedef __attribute__((ext_vector_type(4))) float f32x4;

__device__ inline unsigned short f2bf(float f) {   // round-to-nearest-even
    unsigned u = __float_as_uint(f);
    return (unsigned short)((u + 0x7FFFu + ((u >> 16) & 1u)) >> 16);
}
__device__ inline float bf2f(unsigned short h) {
    return __uint_as_float(((unsigned)h) << 16);
}

// ---------------------------------------------------------------------------
// to_bf16: f32 -> bf16, 8 elems/thread, uint4 stores
// ---------------------------------------------------------------------------
__global__ __launch_bounds__(256) void to_bf16(
    const float* __restrict__ in, unsigned short* __restrict__ outh, int n8) {
    int i = blockIdx.x * blockDim.x + threadIdx.x;
    if (i >= n8) return;
    const float4* p = (const float4*)in + (size_t)i * 2;
    float4 a = p[0], b = p[1];
    union { unsigned short us[8]; uint4 v; } u;
    u.us[0] = f2bf(a.x); u.us[1] = f2bf(a.y); u.us[2] = f2bf(a.z); u.us[3] = f2bf(a.w);
    u.us[4] = f2bf(b.x); u.us[5] = f2bf(b.y); u.us[6] = f2bf(b.z); u.us[7] = f2bf(b.w);
    ((uint4*)outh)[i] = u.v;
}

// ---------------------------------------------------------------------------
// part_hist: per-WG histogram of items into K coarse buckets (LDS counters).
// ---------------------------------------------------------------------------
__global__ __launch_bounds__(256) void part_hist(
    const int* __restrict__ src, const int* __restrict__ dst,
    int* __restrict__ cnt, int nE, int nN, int K, int WGs) {
    __shared__ int lh[1024];
    int wg = blockIdx.x;
    for (int i = threadIdx.x; i < K; i += 256) lh[i] = 0;
    __syncthreads();
    int base = wg * PART_CHUNK;
    int lim = min(base + PART_CHUNK, nE);
    for (int e = base + threadIdx.x; e < lim; e += 256) {
        int s = src[e], t = dst[e];
        atomicAdd(&lh[t >> SHIFT], 1);
        atomicAdd(&lh[(nN + s) >> SHIFT], 1);
    }
    __syncthreads();
    for (int b = threadIdx.x; b < K; b += 256) cnt[b * WGs + wg] = lh[b];
}

// ---------------------------------------------------------------------------
// scan pass 1: per-block sums
// ---------------------------------------------------------------------------
__global__ __launch_bounds__(256) void scan_part(
    const int* __restrict__ in, int* __restrict__ bsum, int n) {
    __shared__ int sdata[256];
    int b = blockIdx.x, t = threadIdx.x;
    int base = b * SCAN_ELEMS + t * 4;
    int s = 0;
#pragma unroll
    for (int k = 0; k < 4; ++k) { int i = base + k; if (i < n) s += in[i]; }
    sdata[t] = s;
    __syncthreads();
    for (int o = 128; o > 0; o >>= 1) {
        if (t < o) sdata[t] += sdata[t + o];
        __syncthreads();
    }
    if (t == 0) bsum[b] = sdata[0];
}

// ---------------------------------------------------------------------------
// scan pass 2: exclusive scan of block sums in place (nb <= 256)
// ---------------------------------------------------------------------------
__global__ __launch_bounds__(256) void scan_tops(int* __restrict__ bsum, int nb) {
    __shared__ int sd[256];
    int t = threadIdx.x;
    int v = (t < nb) ? bsum[t] : 0;
    sd[t] = v;
    __syncthreads();
    for (int o = 1; o < 256; o <<= 1) {
        int u = (t >= o) ? sd[t - o] : 0;
        __syncthreads();
        sd[t] += u;
        __syncthreads();
    }
    if (t < nb) bsum[t] = sd[t] - v;   // exclusive
}

// ---------------------------------------------------------------------------
// scan pass 3: per-chunk exclusive scan + block offset -> out
// ---------------------------------------------------------------------------
__global__ __launch_bounds__(256) void scan_final(
    const int* __restrict__ in, const int* __restrict__ bsum,
    int* __restrict__ out, int n) {
    __shared__ int sth[256];
    int b = blockIdx.x, t = threadIdx.x;
    int base = b * SCAN_ELEMS + t * 4;
    int v[4]; int s = 0;
#pragma unroll
    for (int k = 0; k < 4; ++k) { int i = base + k; v[k] = (i < n) ? in[i] : 0; s += v[k]; }
    sth[t] = s;
    __syncthreads();
    for (int o = 1; o < 256; o <<= 1) {
        int u = (t >= o) ? sth[t - o] : 0;
        __syncthreads();
        sth[t] += u;
        __syncthreads();
    }
    int run = sth[t] - s + bsum[b];
#pragma unroll
    for (int k = 0; k < 4; ++k) {
        int i = base + k;
        if (i < n) { out[i] = run; run += v[k]; }
    }
}

// ---------------------------------------------------------------------------
// part_write: each WG writes items into ITS OWN contiguous slice of each
// bucket region. Single owner + temporally compact -> writeback ~= payload.
// ---------------------------------------------------------------------------
__global__ __launch_bounds__(256) void part_write(
    const int* __restrict__ src, const int* __restrict__ dst,
    const int* __restrict__ scanned, unsigned int* __restrict__ part,
    int nE, int nN, int K, int WGs) {
    __shared__ int cur[1024];
    int wg = blockIdx.x;
    for (int b = threadIdx.x; b < K; b += 256) cur[b] = scanned[b * WGs + wg];
    __syncthreads();
    int base = wg * PART_CHUNK;
    int lim = min(base + PART_CHUNK, nE);
    for (int e = base + threadIdx.x; e < lim; e += 256) {
        int s = src[e], t = dst[e];
        int k1 = t;
        int p1 = atomicAdd(&cur[k1 >> SHIFT], 1);
        part[p1] = ((unsigned)(k1 & (STEP - 1)) << 16) | (unsigned)s;
        int k2 = nN + s;
        int p2 = atomicAdd(&cur[k2 >> SHIFT], 1);
        part[p2] = ((unsigned)(k2 & (STEP - 1)) << 16) | (unsigned)t;
    }
}

// ---------------------------------------------------------------------------
// csr_build: one WG per bucket. LDS degree count + prefix -> off[] exact,
// then scatter u16 vals into the WG-private region.
// ---------------------------------------------------------------------------
__global__ __launch_bounds__(256) void csr_build(
    const unsigned int* __restrict__ part, const int* __restrict__ scanned,
    unsigned short* __restrict__ vals, int* __restrict__ off,
    int n2, int K, int WGs, int totalItems) {
    __shared__ int deg[STEP];
    __shared__ int pfx[STEP];
    int b = blockIdx.x, t = threadIdx.x;
    int base = scanned[b * WGs];
    int endi = (b + 1 < K) ? scanned[(b + 1) * WGs] : totalItems;

    deg[t] = 0;
    __syncthreads();
    for (int i = base + t; i < endi; i += 256)
        atomicAdd(&deg[part[i] >> 16], 1);
    __syncthreads();

    pfx[t] = deg[t];
    __syncthreads();
    for (int o = 1; o < STEP; o <<= 1) {
        int u = (t >= o) ? pfx[t - o] : 0;
        __syncthreads();
        pfx[t] += u;
        __syncthreads();
    }
    int ex = pfx[t] - deg[t];
    int g = b * STEP + t;
    if (g < n2) off[g] = base + ex;
    if (b == K - 1 && t == 0) off[n2] = totalItems;
    deg[t] = ex;           // reuse as bucket-local cursor
    __syncthreads();

    for (int i = base + t; i < endi; i += 256) {
        unsigned u = part[i];
        int l = (int)(u >> 16);
        int p = atomicAdd(&deg[l], 1);
        vals[base + p] = (unsigned short)(u & 0xffffu);
    }
}

// ---------------------------------------------------------------------------
// Kernel A: 512 thr = 8 node-waves. Gather: 8 groups x 8 lanes, ushort8
// (16B/lane) -> 8 rows / 1KB per load instr, 16 rows in flight (unroll 2).
// Butterfly-reduce over group bits (8,16,32). Then rowA/rowX staged bf16 to
// a 4608B padded LDS buffer; waves 0-3 compute H = relu(Aagg@Wn + Ax@Ws + b)
// via 4x mfma_f32_16x16x32_bf16, B-frags from global bf16 W (L1-hot).
// ---------------------------------------------------------------------------
#define ANODES 8
#define ROWB 144   // row stride in bytes: 72 u16 (64 data + 8 pad)
__global__ __launch_bounds__(512) void agg_gemm(
    const unsigned short* __restrict__ Xh,    // [N*D] bf16
    const int* __restrict__ off,              // [2N+1]
    const unsigned short* __restrict__ vals,  // [2E]
    const unsigned short* __restrict__ Whn,   // [64*64] bf16
    const unsigned short* __restrict__ Whs,   // [64*64] bf16
    const float* __restrict__ bias,
    unsigned short* __restrict__ hh, int nNodes) {
    __shared__ __align__(16) unsigned short rows[2][16][72];

    int t = threadIdx.x;
    // zero pad rows 8..15 of both buffers (2 x 8 x 144B = 2304B)
    if (t < 288) {
        int b = t / 144, r = t - b * 144;
        *(unsigned long long*)((char*)&rows[b][8][0] + r * 8) = 0ULL;
    }

    int li = t >> 6;       // wave id = local node 0..7
    int lane = t & 63;
    int g = lane >> 3;     // edge group 0..7
    int q = lane & 7;      // ushort8 chunk: dims 8q..8q+7
    int bb = blockIdx.x * ANODES;
    int node = bb + li;

    float acc[8];
#pragma unroll
    for (int j = 0; j < 8; ++j) acc[j] = 0.f;

    int beg = 0, end = 0;
    if (node < nNodes) { beg = off[node]; end = off[node + 1]; }

    int base = beg;
    for (; base + 16 <= end; base += 16) {
        int s0 = vals[base + g];
        int s1 = vals[base + 8 + g];
        u16x8 v0 = ((const u16x8*)(Xh + (size_t)s0 * D))[q];
        u16x8 v1 = ((const u16x8*)(Xh + (size_t)s1 * D))[q];
#pragma unroll
        for (int j = 0; j < 8; ++j) acc[j] += bf2f(v0[j]) + bf2f(v1[j]);
    }
    for (; base + 8 <= end; base += 8) {
        int s0 = vals[base + g];
        u16x8 v0 = ((const u16x8*)(Xh + (size_t)s0 * D))[q];
#pragma unroll
        for (int j = 0; j < 8; ++j) acc[j] += bf2f(v0[j]);
    }
    int rem = end - base;
    if (g < rem) {
        int s0 = vals[base + g];
        u16x8 v0 = ((const u16x8*)(Xh + (size_t)s0 * D))[q];
#pragma unroll
        for (int j = 0; j < 8; ++j) acc[j] += bf2f(v0[j]);
    }
    // reduce across the 8 edge-groups (lane bits 3,4,5)
#pragma unroll
    for (int j = 0; j < 8; ++j) {
        acc[j] += __shfl_xor(acc[j], 8);
        acc[j] += __shfl_xor(acc[j], 16);
        acc[j] += __shfl_xor(acc[j], 32);
    }

    if (node < nNodes && g == 0) {
        float inv = 1.0f / fmaxf((float)(end - beg), 1.0f);
        u16x8 mv;
#pragma unroll
        for (int j = 0; j < 8; ++j) mv[j] = f2bf(acc[j] * inv);
        *(u16x8*)((char*)&rows[0][li][0] + q * 16) = mv;
        u16x8 xv = ((const u16x8*)(Xh + (size_t)node * D))[q];
        *(u16x8*)((char*)&rows[1][li][0] + q * 16) = xv;
    }
    __syncthreads();

    // ---- MFMA GEMM: waves 0..3, wave li owns N-tile li (cols li*16..+15) --
    if (li >= 4) return;
    int c = lane & 15;     // A row index / B+C col index
    int hi = lane >> 4;    // k-group / C row-group
    f32x4 accm;
    float bv = bias[li * 16 + c];
    accm[0] = bv; accm[1] = bv; accm[2] = bv; accm[3] = bv;
#pragma unroll
    for (int kh = 0; kh < 2; ++kh) {
        bf16x8 aA = *(const bf16x8*)((const char*)&rows[0][0][0] + c * ROWB + kh * 64 + hi * 16);
        bf16x8 aX = *(const bf16x8*)((const char*)&rows[1][0][0] + c * ROWB + kh * 64 + hi * 16);
        bf16x8 bN, bS;
        int kb = kh * 32 + hi * 8;
#pragma unroll
        for (int j = 0; j < 8; ++j) {
            bN[j] = (short)Whn[(size_t)(kb + j) * D + li * 16 + c];
            bS[j] = (short)Whs[(size_t)(kb + j) * D + li * 16 + c];
        }
        accm = __builtin_amdgcn_mfma_f32_16x16x32_bf16(aA, bN, accm, 0, 0, 0);
        accm = __builtin_amdgcn_mfma_f32_16x16x32_bf16(aX, bS, accm, 0, 0, 0);
    }
    // C/D layout (m89-verified): col = lane&15, row = (lane>>4)*4 + reg
#pragma unroll
    for (int r = 0; r < 4; ++r) {
        int row = hi * 4 + r;
        if (row < 8) {
            int n2a = bb + row;
            if (n2a < nNodes)
                hh[(size_t)n2a * D + li * 16 + c] = f2bf(fmaxf(accm[r], 0.0f));
        }
    }
}

// ---------------------------------------------------------------------------
// Kernel B: per-node wave over outgoing edges; same 8x8 group structure,
// ushort8 h gather; squared diffs in f32; tanh(mean) -> f32 out.
// off[nNodes+node] indexes vals [E,2E) directly.
// ---------------------------------------------------------------------------
__global__ __launch_bounds__(256) void m_gather(
    const unsigned short* __restrict__ hh,    // [N*D] bf16
    const int* __restrict__ off,              // [2N+1], src section at [N..2N]
    const unsigned short* __restrict__ vals,  // [2E]
    float* __restrict__ out, int nNodes) {
    int t = threadIdx.x;
    int li = t >> 6;
    int lane = t & 63;
    int g = lane >> 3;     // edge group 0..7
    int q = lane & 7;      // ushort8 chunk: dims 8q..8q+7
    int node = blockIdx.x * 4 + li;
    if (node >= nNodes) return;

    u16x8 hv = ((const u16x8*)(hh + (size_t)node * D))[q];
    float hn[8];
#pragma unroll
    for (int j = 0; j < 8; ++j) hn[j] = bf2f(hv[j]);

    int beg = off[nNodes + node];
    int end = off[nNodes + node + 1];

    float acc[8];
#pragma unroll
    for (int j = 0; j < 8; ++j) acc[j] = 0.f;

    int base = beg;
    for (; base + 16 <= end; base += 16) {
        int t0 = vals[base + g];
        int t1 = vals[base + 8 + g];
        u16x8 u0 = ((const u16x8*)(hh + (size_t)t0 * D))[q];
        u16x8 u1 = ((const u16x8*)(hh + (size_t)t1 * D))[q];
#pragma unroll
        for (int j = 0; j < 8; ++j) {
            float d0 = hn[j] - bf2f(u0[j]);
            float d1 = hn[j] - bf2f(u1[j]);
            acc[j] += d0 * d0 + d1 * d1;
        }
    }
    for (; base + 8 <= end; base += 8) {
        int t0 = vals[base + g];
        u16x8 u0 = ((const u16x8*)(hh + (size_t)t0 * D))[q];
#pragma unroll
        for (int j = 0; j < 8; ++j) {
            float d0 = hn[j] - bf2f(u0[j]);
            acc[j] += d0 * d0;
        }
    }
    int rem = end - base;
    if (g < rem) {
        int t0 = vals[base + g];
        u16x8 u0 = ((const u16x8*)(hh + (size_t)t0 * D))[q];
#pragma unroll
        for (int j = 0; j < 8; ++j) {
            float d0 = hn[j] - bf2f(u0[j]);
            acc[j] += d0 * d0;
        }
    }
#pragma unroll
    for (int j = 0; j < 8; ++j) {
        acc[j] += __shfl_xor(acc[j], 8);
        acc[j] += __shfl_xor(acc[j], 16);
        acc[j] += __shfl_xor(acc[j], 32);
    }

    if (g == 0) {
        float inv = 1.0f / fmaxf((float)(end - beg), 1.0f);
        float4 r0, r1;
        r0.x = tanhf(acc[0] * inv); r0.y = tanhf(acc[1] * inv);
        r0.z = tanhf(acc[2] * inv); r0.w = tanhf(acc[3] * inv);
        r1.x = tanhf(acc[4] * inv); r1.y = tanhf(acc[5] * inv);
        r1.z = tanhf(acc[6] * inv); r1.w = tanhf(acc[7] * inv);
        ((float4*)(out + (size_t)node * D))[q * 2] = r0;
        ((float4*)(out + (size_t)node * D))[q * 2 + 1] = r1;
    }
}

extern "C" void kernel_launch(void* const* d_in, const int* in_sizes, int n_in,
                              void* d_out, int out_size, void* d_ws, size_t ws_size,
                              hipStream_t stream) {
    const float* X  = (const float*)d_in[0];
    const int*   ei = (const int*)d_in[1];   // int32 (JAX canonicalized)
    const float* Wn = (const float*)d_in[2];
    const float* Ws = (const float*)d_in[3];
    const float* b  = (const float*)d_in[4];
    float* out = (float*)d_out;

    int nNodes = in_sizes[0] / D;
    int nEdges = in_sizes[1] / 2;
    const int* src = ei;
    const int* dst = ei + nEdges;

    int n2 = 2 * nNodes;                       // item key space
    int K = (n2 + STEP - 1) / STEP;            // 391 for N=50k
    int WGs = (nEdges + PART_CHUNK - 1) / PART_CHUNK;  // 391
    int nCnt = K * WGs;
    int nb = (nCnt + SCAN_ELEMS - 1) / SCAN_ELEMS;
    int totalItems = 2 * nEdges;

    // workspace (16B-aligned sections, 4B elems):
    // cnt[K*WGs] | scanned[K*WGs] | bsum[256] | off[2N+1] | part[2E u32]
    // | vals[2E u16] | Xh[N*D u16] | hh[N*D u16] | Whn[4096 u16] | Whs[...]
    size_t o = 0;
    auto align4 = [](size_t x) { return (x + 3) & ~(size_t)3; };
    int* cnt     = (int*)d_ws;                 o = align4((size_t)nCnt);
    int* scanned = (int*)d_ws + o;             o = align4(o + (size_t)nCnt);
    int* bsum    = (int*)d_ws + o;             o = align4(o + 256);
    int* off     = (int*)d_ws + o;             o = align4(o + (size_t)n2 + 1);
    unsigned int* part = (unsigned int*)((int*)d_ws + o);
    o = align4(o + 2 * (size_t)nEdges);
    unsigned short* vals = (unsigned short*)((int*)d_ws + o);
    o = align4(o + (size_t)nEdges);            // 2E u16 == E ints
    unsigned short* Xh = (unsigned short*)((int*)d_ws + o);
    o = align4(o + (size_t)nNodes * D / 2);    // N*D u16
    unsigned short* hh = (unsigned short*)((int*)d_ws + o);
    o = align4(o + (size_t)nNodes * D / 2);
    unsigned short* Whn = (unsigned short*)((int*)d_ws + o);
    o = align4(o + (size_t)(D * D) / 2);
    unsigned short* Whs = (unsigned short*)((int*)d_ws + o);

    int n8 = nNodes * D / 8;
    to_bf16<<<(n8 + 255) / 256, 256, 0, stream>>>(X, Xh, n8);
    to_bf16<<<2, 256, 0, stream>>>(Wn, Whn, D * D / 8);
    to_bf16<<<2, 256, 0, stream>>>(Ws, Whs, D * D / 8);

    part_hist<<<WGs, 256, 0, stream>>>(src, dst, cnt, nEdges, nNodes, K, WGs);
    scan_part<<<nb, 256, 0, stream>>>(cnt, bsum, nCnt);
    scan_tops<<<1, 256, 0, stream>>>(bsum, nb);
    scan_final<<<nb, 256, 0, stream>>>(cnt, bsum, scanned, nCnt);
    part_write<<<WGs, 256, 0, stream>>>(src, dst, scanned, part, nEdges, nNodes, K, WGs);
    csr_build<<<K, STEP, 0, stream>>>(part, scanned, vals, off, n2, K, WGs, totalItems);

    int aBlocks = (nNodes + ANODES - 1) / ANODES;
    agg_gemm<<<aBlocks, 512, 0, stream>>>(Xh, off, vals, Whn, Whs, b, hh, nNodes);
    int mBlocks = (nNodes + 3) / 4;
    m_gather<<<mBlocks, 256, 0, stream>>>(hh, off, vals, out, nNodes);
}